// Round 1
// baseline (813.605 us; speedup 1.0000x reference)
//
#include <hip/hip_runtime.h>
#include <math.h>

#define Bb 2
#define Cc 64
#define Ff 128
#define Tt 250
#define Kk 8
#define TnN 243
#define Hh 32
#define Nn 256
#define EPS_ 1e-5f
#define TPAD 68

// ---------------- stats: per-batch sum & sumsq ----------------
__global__ void k_stats(const float* __restrict__ x, float* __restrict__ stats) {
    int b = blockIdx.y;
    const float* xb = x + (size_t)b * Cc * Ff * Tt;
    const int n = Cc * Ff * Tt;
    float s = 0.f, s2 = 0.f;
    for (int i = blockIdx.x * blockDim.x + threadIdx.x; i < n; i += gridDim.x * blockDim.x) {
        float v = xb[i];
        s += v; s2 += v * v;
    }
    for (int off = 32; off; off >>= 1) {
        s  += __shfl_down(s, off);
        s2 += __shfl_down(s2, off);
    }
    __shared__ float ls[8], ls2[8];
    int lane = threadIdx.x & 63, w = threadIdx.x >> 6;
    if (lane == 0) { ls[w] = s; ls2[w] = s2; }
    __syncthreads();
    if (threadIdx.x == 0) {
        float a = 0.f, a2 = 0.f;
        int nw = blockDim.x >> 6;
        for (int i = 0; i < nw; i++) { a += ls[i]; a2 += ls2[i]; }
        atomicAdd(&stats[b * 2 + 0], a);
        atomicAdd(&stats[b * 2 + 1], a2);
    }
}

// ---------------- normalize + write xu[n][c][t] ----------------
__global__ void k_norm(const float* __restrict__ x, const float* __restrict__ stats,
                       const float* __restrict__ gamma, const float* __restrict__ beta,
                       float* __restrict__ xu) {
    int idx = blockIdx.x * blockDim.x + threadIdx.x;
    const int total = Nn * Cc * Tt;
    if (idx >= total) return;
    int t = idx % Tt;
    int c = (idx / Tt) % Cc;
    int n = idx / (Tt * Cc);
    int b = n >> 7, f = n & 127;
    const float inv = 1.0f / (float)(Cc * Ff * Tt);
    float mean = stats[b * 2 + 0] * inv;
    float var  = stats[b * 2 + 1] * inv - mean * mean;
    float rstd = rsqrtf(var + EPS_);
    float v = x[(((size_t)(b * Cc + c)) * Ff + f) * Tt + t];
    xu[idx] = (v - mean) * rstd * gamma[c] + beta[c];
}

// ---------------- pack conv weight: Wc[(i*8+k)][o] = wct[i][o][k] ----------------
__global__ void k_packwc(const float* __restrict__ wct, float* __restrict__ Wc) {
    int idx = blockIdx.x * blockDim.x + threadIdx.x;
    if (idx >= 512 * 64) return;
    int o = idx & 63;
    int ik = idx >> 6;
    int i = ik >> 3, k = ik & 7;
    Wc[idx] = wct[((size_t)i * 64 + o) * 8 + k];
}

// ---------------- layer 0 GEMM: U[t][n][j] = sum_{c,k} xu[n][c][t+k] * W0[dir][c*8+k][j'] ----------------
__global__ __launch_bounds__(256) void k_gemm0(const float* __restrict__ xu,
                                               const float* __restrict__ W0,
                                               float* __restrict__ U) {
    __shared__ float AsT[64][TPAD];
    __shared__ float Bs[64][TPAD];
    int t  = blockIdx.x;
    int n0 = blockIdx.y * 64;
    int j0 = blockIdx.z * 64;
    int tid = threadIdx.x;
    int tx = tid & 15, ty = tid >> 4;
    float acc[4][4] = {};
    for (int kk0 = 0; kk0 < 512; kk0 += 64) {
        // stage A^T: AsT[p][i] = xu[n0+i][c][t+k], p = (c*8+k) - kk0
        int p = tid & 63;
        int i0 = tid >> 6;
        int c = (kk0 + p) >> 3;
        int k = p & 7;
        const float* srcA = xu + (size_t)c * Tt + t + k;
        #pragma unroll
        for (int ii = 0; ii < 16; ii++) {
            int i = i0 + ii * 4;
            AsT[p][i] = srcA[(size_t)(n0 + i) * (Cc * Tt)];
        }
        // stage B: Bs[pr][jj] = W0[dir][kk0+pr][col0]
        int jj = tid & 63;
        int pr0 = tid >> 6;
        int dir = j0 >> 7;
        int col0 = (j0 & 127) + jj;
        #pragma unroll
        for (int pp = 0; pp < 16; pp++) {
            int pr = pr0 + pp * 4;
            Bs[pr][jj] = W0[((size_t)dir * 512 + kk0 + pr) * 128 + col0];
        }
        __syncthreads();
        #pragma unroll 16
        for (int p2 = 0; p2 < 64; p2++) {
            float4 a = *(const float4*)&AsT[p2][ty * 4];
            float4 b = *(const float4*)&Bs[p2][tx * 4];
            float av[4] = {a.x, a.y, a.z, a.w};
            float bv[4] = {b.x, b.y, b.z, b.w};
            #pragma unroll
            for (int r = 0; r < 4; r++)
                #pragma unroll
                for (int q = 0; q < 4; q++)
                    acc[r][q] = fmaf(av[r], bv[q], acc[r][q]);
        }
        __syncthreads();
    }
    #pragma unroll
    for (int r = 0; r < 4; r++) {
        int n = n0 + ty * 4 + r;
        size_t base = ((size_t)t * Nn + n) * 256 + j0 + tx * 4;
        float4 o4 = make_float4(acc[r][0], acc[r][1], acc[r][2], acc[r][3]);
        *(float4*)&U[base] = o4;
    }
}

// ---------------- layers 1..3 GEMM: U[m][j] = sum_i hin[m][i] * Wr[l][dir][i][j'] ----------------
__global__ __launch_bounds__(256) void k_gemmr(const float* __restrict__ hin,
                                               const float* __restrict__ Wr,
                                               float* __restrict__ U, int layer) {
    __shared__ float AsT[64][TPAD];
    __shared__ float Bs[64][TPAD];
    int m0 = blockIdx.x * 64;
    int j0 = blockIdx.y * 64;
    int tid = threadIdx.x;
    // stage A^T
    int i = tid & 63, ml0 = tid >> 6;
    #pragma unroll
    for (int mm = 0; mm < 16; mm++) {
        int ml = ml0 + mm * 4;
        AsT[i][ml] = hin[(size_t)(m0 + ml) * 64 + i];
    }
    // stage B
    int jj = tid & 63, pr0 = tid >> 6;
    int dir = j0 >> 7;
    int col0 = (j0 & 127) + jj;
    const float* W = Wr + (size_t)((layer - 1) * 2 + dir) * 64 * 128;
    #pragma unroll
    for (int pp = 0; pp < 16; pp++) {
        int pr = pr0 + pp * 4;
        Bs[pr][jj] = W[pr * 128 + col0];
    }
    __syncthreads();
    int tx = tid & 15, ty = tid >> 4;
    float acc[4][4] = {};
    #pragma unroll 16
    for (int p = 0; p < 64; p++) {
        float4 a = *(const float4*)&AsT[p][ty * 4];
        float4 b = *(const float4*)&Bs[p][tx * 4];
        float av[4] = {a.x, a.y, a.z, a.w};
        float bv[4] = {b.x, b.y, b.z, b.w};
        #pragma unroll
        for (int r = 0; r < 4; r++)
            #pragma unroll
            for (int q = 0; q < 4; q++)
                acc[r][q] = fmaf(av[r], bv[q], acc[r][q]);
    }
    #pragma unroll
    for (int r = 0; r < 4; r++) {
        size_t base = (size_t)(m0 + ty * 4 + r) * 256 + j0 + tx * 4;
        float4 o4 = make_float4(acc[r][0], acc[r][1], acc[r][2], acc[r][3]);
        *(float4*)&U[base] = o4;
    }
}

// ---------------- SRU scan: one layer, both directions ----------------
__global__ __launch_bounds__(256) void k_scan(const float* __restrict__ U,
                                              const float* __restrict__ v,
                                              const float* __restrict__ bbias,
                                              float* __restrict__ hout, int layer) {
    const int G = 8;
    int d = blockIdx.y;
    int h = threadIdx.x & 31;
    int nl = threadIdx.x >> 5;
    int n = blockIdx.x * 8 + nl;
    const float* vv = v + (size_t)(layer * 2 + d) * 64;
    const float* bv = bbias + (size_t)(layer * 2 + d) * 64;
    float vf = vv[h], vr = vv[32 + h], bf = bv[h], br = bv[32 + h];
    const float* Ub = U + (size_t)n * 256 + d * 128 + h;
    float* Ho = hout + (size_t)n * 64 + d * 32 + h;
    const size_t stepU = (size_t)Nn * 256;
    const size_t stepH = (size_t)Nn * 64;
    int t0 = d ? (TnN - 1) : 0;
    int dt = d ? -1 : 1;
    float cz[G], cf[G], cr[G], cx[G];
    #pragma unroll
    for (int u = 0; u < G; u++) {
        const float* p = Ub + (size_t)(t0 + dt * u) * stepU;
        cz[u] = p[0]; cf[u] = p[32]; cr[u] = p[64]; cx[u] = p[96];
    }
    float c = 0.f;
    for (int g0 = 0; g0 < TnN; g0 += G) {
        float nz[G], nf[G], nr[G], nx[G];
        int g1 = g0 + G;
        #pragma unroll
        for (int u = 0; u < G; u++) {
            int g = g1 + u;
            if (g < TnN) {
                const float* p = Ub + (size_t)(t0 + dt * g) * stepU;
                nz[u] = p[0]; nf[u] = p[32]; nr[u] = p[64]; nx[u] = p[96];
            } else { nz[u] = 0.f; nf[u] = 0.f; nr[u] = 0.f; nx[u] = 0.f; }
        }
        #pragma unroll
        for (int u = 0; u < G; u++) {
            int g = g0 + u;
            if (g < TnN) {
                float fgate = 1.f / (1.f + __expf(-(cf[u] + vf * c + bf)));
                float rgate = 1.f / (1.f + __expf(-(cr[u] + vr * c + br)));
                c = fgate * c + (1.f - fgate) * cz[u];
                float hv = rgate * c + (1.f - rgate) * cx[u];
                Ho[(size_t)(t0 + dt * g) * stepH] = hv;
            }
        }
        #pragma unroll
        for (int u = 0; u < G; u++) { cz[u] = nz[u]; cf[u] = nf[u]; cr[u] = nr[u]; cx[u] = nx[u]; }
    }
}

// ---------------- final conv (as windowed GEMM) + bias + residual + transpose out ----------------
__global__ __launch_bounds__(256) void k_conv(const float* __restrict__ hL,
                                              const float* __restrict__ Wc,
                                              const float* __restrict__ bct,
                                              const float* __restrict__ x,
                                              float* __restrict__ out) {
    __shared__ float AsT[64][TPAD];
    __shared__ float Bs[64][TPAD];
    int t  = blockIdx.x;      // 0..249
    int n0 = blockIdx.y * 64;
    int tid = threadIdx.x;
    int tx = tid & 15, ty = tid >> 4;
    float acc[4][4] = {};
    for (int kk0 = 0; kk0 < 512; kk0 += 64) {
        int p = tid & 63;
        int i0 = tid >> 6;
        int ci = (kk0 + p) >> 3;
        int k = p & 7;
        int tau = t - k;
        bool ok = (tau >= 0) && (tau < TnN);
        #pragma unroll
        for (int ii = 0; ii < 16; ii++) {
            int nl = i0 + ii * 4;
            AsT[p][nl] = ok ? hL[((size_t)tau * Nn + n0 + nl) * 64 + ci] : 0.f;
        }
        int jj = tid & 63, pr0 = tid >> 6;
        #pragma unroll
        for (int pp = 0; pp < 16; pp++) {
            int pr = pr0 + pp * 4;
            Bs[pr][jj] = Wc[(size_t)(kk0 + pr) * 64 + jj];
        }
        __syncthreads();
        #pragma unroll 16
        for (int p2 = 0; p2 < 64; p2++) {
            float4 a = *(const float4*)&AsT[p2][ty * 4];
            float4 b = *(const float4*)&Bs[p2][tx * 4];
            float av[4] = {a.x, a.y, a.z, a.w};
            float bv[4] = {b.x, b.y, b.z, b.w};
            #pragma unroll
            for (int r = 0; r < 4; r++)
                #pragma unroll
                for (int q = 0; q < 4; q++)
                    acc[r][q] = fmaf(av[r], bv[q], acc[r][q]);
        }
        __syncthreads();
    }
    #pragma unroll
    for (int r = 0; r < 4; r++) {
        int n = n0 + ty * 4 + r;
        int b = n >> 7, f = n & 127;
        #pragma unroll
        for (int q = 0; q < 4; q++) {
            int o = tx * 4 + q;
            size_t oidx = (((size_t)(b * Cc + o)) * Ff + f) * Tt + t;
            out[oidx] = acc[r][q] + bct[o] + x[oidx];
        }
    }
}

extern "C" void kernel_launch(void* const* d_in, const int* in_sizes, int n_in,
                              void* d_out, int out_size, void* d_ws, size_t ws_size,
                              hipStream_t stream) {
    (void)in_sizes; (void)n_in; (void)out_size; (void)ws_size;
    const float* x     = (const float*)d_in[0];
    const float* gamma = (const float*)d_in[1];
    const float* beta  = (const float*)d_in[2];
    const float* W0    = (const float*)d_in[3];
    const float* Wr    = (const float*)d_in[4];
    const float* v     = (const float*)d_in[5];
    const float* bb    = (const float*)d_in[6];
    const float* wct   = (const float*)d_in[7];
    const float* bct   = (const float*)d_in[8];
    float* out = (float*)d_out;

    float* f0    = (float*)d_ws;
    float* stats = f0;                                   // 16 floats
    float* xu    = f0 + 16;                              // Nn*Cc*Tt = 4,096,000
    float* U     = xu + (size_t)Nn * Cc * Tt;            // TnN*Nn*256 = 15,925,248
    float* h1    = U + (size_t)TnN * Nn * 256;           // TnN*Nn*64 = 3,981,312
    float* Wc    = h1 + (size_t)TnN * Nn * 64;           // 32,768
    float* h0    = xu;                                   // alias: xu dead after k_gemm0

    hipMemsetAsync(stats, 0, 16, stream);
    k_stats<<<dim3(128, 2), 256, 0, stream>>>(x, stats);
    k_norm<<<(Nn * Cc * Tt + 255) / 256, 256, 0, stream>>>(x, stats, gamma, beta, xu);
    k_packwc<<<(512 * 64 + 255) / 256, 256, 0, stream>>>(wct, Wc);

    k_gemm0<<<dim3(TnN, 4, 4), 256, 0, stream>>>(xu, W0, U);
    k_scan<<<dim3(32, 2), 256, 0, stream>>>(U, v, bb, h0, 0);

    k_gemmr<<<dim3(972, 4), 256, 0, stream>>>(h0, Wr, U, 1);
    k_scan<<<dim3(32, 2), 256, 0, stream>>>(U, v, bb, h1, 1);

    k_gemmr<<<dim3(972, 4), 256, 0, stream>>>(h1, Wr, U, 2);
    k_scan<<<dim3(32, 2), 256, 0, stream>>>(U, v, bb, h0, 2);

    k_gemmr<<<dim3(972, 4), 256, 0, stream>>>(h0, Wr, U, 3);
    k_scan<<<dim3(32, 2), 256, 0, stream>>>(U, v, bb, h1, 3);

    k_conv<<<dim3(Tt, 4), 256, 0, stream>>>(h1, Wc, bct, x, out);
}

// Round 2
// 655.450 us; speedup vs baseline: 1.2413x; 1.2413x over previous
//
#include <hip/hip_runtime.h>
#include <math.h>

#define Tt 250
#define TnN 243
#define Nn 256
#define EPS_ 1e-5f

typedef unsigned short u16;
typedef __bf16 bf16x8 __attribute__((ext_vector_type(8)));
typedef float f32x4 __attribute__((ext_vector_type(4)));

__device__ __forceinline__ u16 f2bf(float f) {
    unsigned u = __builtin_bit_cast(unsigned, f);
    u += 0x7FFFu + ((u >> 16) & 1u);
    return (u16)(u >> 16);
}
__device__ __forceinline__ float bf2f(u16 s) {
    unsigned u = ((unsigned)s) << 16;
    return __builtin_bit_cast(float, u);
}

// ---------------- stats: per-batch sum & sumsq ----------------
__global__ void k_stats(const float* __restrict__ x, float* __restrict__ stats) {
    int b = blockIdx.y;
    const float* xb = x + (size_t)b * 64 * 128 * Tt;
    const int n = 64 * 128 * Tt;
    float s = 0.f, s2 = 0.f;
    for (int i = blockIdx.x * blockDim.x + threadIdx.x; i < n; i += gridDim.x * blockDim.x) {
        float v = xb[i];
        s += v; s2 += v * v;
    }
    for (int off = 32; off; off >>= 1) {
        s  += __shfl_down(s, off);
        s2 += __shfl_down(s2, off);
    }
    __shared__ float ls[8], ls2[8];
    int lane = threadIdx.x & 63, w = threadIdx.x >> 6;
    if (lane == 0) { ls[w] = s; ls2[w] = s2; }
    __syncthreads();
    if (threadIdx.x == 0) {
        float a = 0.f, a2 = 0.f;
        int nw = blockDim.x >> 6;
        for (int i = 0; i < nw; i++) { a += ls[i]; a2 += ls2[i]; }
        atomicAdd(&stats[b * 2 + 0], a);
        atomicAdd(&stats[b * 2 + 1], a2);
    }
}

// ---------------- normalize + write xu[n][c][t] (t padded to 256) ----------------
__global__ void k_norm(const float* __restrict__ x, const float* __restrict__ stats,
                       const float* __restrict__ gamma, const float* __restrict__ beta,
                       float* __restrict__ xu) {
    int idx = blockIdx.x * blockDim.x + threadIdx.x;
    const int total = Nn * 64 * Tt;
    if (idx >= total) return;
    int t = idx % Tt;
    int c = (idx / Tt) & 63;
    int n = idx / (Tt * 64);
    int b = n >> 7, f = n & 127;
    const float inv = 1.0f / (float)(64 * 128 * Tt);
    float mean = stats[b * 2 + 0] * inv;
    float var  = stats[b * 2 + 1] * inv - mean * mean;
    float rstd = rsqrtf(var + EPS_);
    float v = x[(((size_t)(b * 64 + c)) * 128 + f) * Tt + t];
    xu[((size_t)(n * 64 + c) << 8) + t] = (v - mean) * rstd * gamma[c] + beta[c];
}

// ---------------- pack all weights to bf16 (transposed to [out][k] layouts) ----------------
__global__ void k_packw(const float* __restrict__ W0, const float* __restrict__ Wr,
                        const float* __restrict__ wct,
                        u16* __restrict__ W0t, u16* __restrict__ Wrt, u16* __restrict__ Wcto) {
    int idx = blockIdx.x * blockDim.x + threadIdx.x;
    if (idx < 131072) {
        // W0t[j(256)][p(512)] = W0[j>>7][p][j&127]
        int j = idx >> 9, p = idx & 511;
        W0t[idx] = f2bf(W0[(size_t)(j >> 7) * 65536 + p * 128 + (j & 127)]);
    } else if (idx < 180224) {
        // Wrt[l-1][j(256)][i(64)] = Wr[l-1][j>>7][i][j&127]
        int r = idx - 131072;
        int i = r & 63, j = (r >> 6) & 255, lidx = r >> 14;
        Wrt[r] = f2bf(Wr[(size_t)(lidx * 2 + (j >> 7)) * 8192 + i * 128 + (j & 127)]);
    } else if (idx < 212992) {
        // Wcto[o(64)][kk*64+ci] = wct[ci][o][kk]
        int r = idx - 180224;
        int o = r >> 9; int k = r & 511; int kk = k >> 6, ci = k & 63;
        Wcto[r] = f2bf(wct[(size_t)ci * 512 + o * 8 + kk]);
    }
}

// ---------------- im2col: Abig[t*256+n][c*8+kk] = bf16(xu[n][c][t+kk]) ----------------
__global__ __launch_bounds__(256) void k_im2col(const float* __restrict__ xu, u16* __restrict__ A) {
    __shared__ u16 lx[8][64][40];
    int t0 = blockIdx.x * 32;   // 8 tiles
    int n0 = blockIdx.y * 8;    // 32 tiles
    int tid = threadIdx.x;
    #pragma unroll
    for (int it = 0; it < 20; ++it) {
        int task = tid + it * 256;       // 5120 tasks
        int v = task % 10;
        int c = (task / 10) & 63;
        int nn = task / 640;
        float4 f4 = *(const float4*)&xu[((size_t)((n0 + nn) * 64 + c) << 8) + t0 + v * 4];
        lx[nn][c][v * 4 + 0] = f2bf(f4.x);
        lx[nn][c][v * 4 + 1] = f2bf(f4.y);
        lx[nn][c][v * 4 + 2] = f2bf(f4.z);
        lx[nn][c][v * 4 + 3] = f2bf(f4.w);
    }
    __syncthreads();
    for (int it = 0; it < 64; ++it) {
        int task = it * 256 + tid;
        int c = task & 63, nn = (task >> 6) & 7, tt = task >> 9;
        int t = t0 + tt;
        if (t >= TnN) break;             // tt uniform per iteration
        u16 tmp[8];
        #pragma unroll
        for (int j = 0; j < 8; ++j) tmp[j] = lx[nn][c][tt + j];
        uint4 o;
        o.x = (unsigned)tmp[0] | ((unsigned)tmp[1] << 16);
        o.y = (unsigned)tmp[2] | ((unsigned)tmp[3] << 16);
        o.z = (unsigned)tmp[4] | ((unsigned)tmp[5] << 16);
        o.w = (unsigned)tmp[6] | ((unsigned)tmp[7] << 16);
        *(uint4*)&A[((size_t)t * 256 + n0 + nn) * 512 + c * 8] = o;
    }
}

// ---------------- MFMA GEMM: U[m][j] = Abig[m][512] x W0t[j][512]^T, 128x128 tile ----------------
__global__ __launch_bounds__(256) void k_gemm0m(const u16* __restrict__ A,
                                                const u16* __restrict__ B,
                                                u16* __restrict__ U) {
    __shared__ u16 sh[16384];
    u16* As = sh;            // 128 rows x 32 k, stride 40
    u16* Bs = sh + 5120;
    const int tid = threadIdx.x;
    const size_t m0 = (size_t)blockIdx.x * 128;
    const int j0 = blockIdx.y * 128;
    const int lane = tid & 63, w = tid >> 6;
    const int wr = w >> 1, wc = w & 1;
    const int ml = lane & 15, q = lane >> 4;
    f32x4 acc[4][4] = {};
    for (int kc = 0; kc < 16; ++kc) {
        int c0 = kc * 32;
        #pragma unroll
        for (int i = 0; i < 2; ++i) {
            int task = tid + i * 256;
            int row = task >> 2, grp = task & 3;
            *(uint4*)&As[row * 40 + grp * 8] = *(const uint4*)&A[(m0 + row) * 512 + c0 + grp * 8];
            *(uint4*)&Bs[row * 40 + grp * 8] = *(const uint4*)&B[(size_t)(j0 + row) * 512 + c0 + grp * 8];
        }
        __syncthreads();
        bf16x8 af[4], bfv[4];
        #pragma unroll
        for (int mt = 0; mt < 4; ++mt) af[mt] = *(const bf16x8*)&As[(wr * 64 + mt * 16 + ml) * 40 + q * 8];
        #pragma unroll
        for (int nt = 0; nt < 4; ++nt) bfv[nt] = *(const bf16x8*)&Bs[(wc * 64 + nt * 16 + ml) * 40 + q * 8];
        #pragma unroll
        for (int mt = 0; mt < 4; ++mt)
            #pragma unroll
            for (int nt = 0; nt < 4; ++nt)
                acc[mt][nt] = __builtin_amdgcn_mfma_f32_16x16x32_bf16(af[mt], bfv[nt], acc[mt][nt], 0, 0, 0);
        __syncthreads();
    }
    // epilogue via LDS for coalesced bf16 stores
    u16* Cw = sh + w * 4096;
    #pragma unroll
    for (int mt = 0; mt < 4; ++mt)
        #pragma unroll
        for (int nt = 0; nt < 4; ++nt)
            #pragma unroll
            for (int r = 0; r < 4; ++r)
                Cw[(mt * 16 + q * 4 + r) * 64 + nt * 16 + ml] = f2bf(acc[mt][nt][r]);
    __syncthreads();
    #pragma unroll
    for (int it = 0; it < 8; ++it) {
        int task = it * 64 + lane;
        int grp = task & 7, row = task >> 3;
        size_t gr = m0 + wr * 64 + row;
        *(uint4*)&U[gr * 256 + j0 + wc * 64 + grp * 8] = *(const uint4*)&Cw[row * 64 + grp * 8];
    }
}

// ---------------- MFMA GEMM layers 1..3: U[m][j] = h[m][64] x Wt[j][64]^T ----------------
__global__ __launch_bounds__(256) void k_gemmr(const u16* __restrict__ h,
                                               const u16* __restrict__ Wt,
                                               u16* __restrict__ U) {
    __shared__ u16 sh[16384];
    u16* As = sh;
    u16* Bs = sh + 5120;
    const int tid = threadIdx.x;
    const size_t m0 = (size_t)blockIdx.x * 128;
    const int j0 = blockIdx.y * 128;
    const int lane = tid & 63, w = tid >> 6;
    const int wr = w >> 1, wc = w & 1;
    const int ml = lane & 15, q = lane >> 4;
    f32x4 acc[4][4] = {};
    for (int kc = 0; kc < 2; ++kc) {
        int c0 = kc * 32;
        #pragma unroll
        for (int i = 0; i < 2; ++i) {
            int task = tid + i * 256;
            int row = task >> 2, grp = task & 3;
            *(uint4*)&As[row * 40 + grp * 8] = *(const uint4*)&h[(m0 + row) * 64 + c0 + grp * 8];
            *(uint4*)&Bs[row * 40 + grp * 8] = *(const uint4*)&Wt[(size_t)(j0 + row) * 64 + c0 + grp * 8];
        }
        __syncthreads();
        bf16x8 af[4], bfv[4];
        #pragma unroll
        for (int mt = 0; mt < 4; ++mt) af[mt] = *(const bf16x8*)&As[(wr * 64 + mt * 16 + ml) * 40 + q * 8];
        #pragma unroll
        for (int nt = 0; nt < 4; ++nt) bfv[nt] = *(const bf16x8*)&Bs[(wc * 64 + nt * 16 + ml) * 40 + q * 8];
        #pragma unroll
        for (int mt = 0; mt < 4; ++mt)
            #pragma unroll
            for (int nt = 0; nt < 4; ++nt)
                acc[mt][nt] = __builtin_amdgcn_mfma_f32_16x16x32_bf16(af[mt], bfv[nt], acc[mt][nt], 0, 0, 0);
        __syncthreads();
    }
    u16* Cw = sh + w * 4096;
    #pragma unroll
    for (int mt = 0; mt < 4; ++mt)
        #pragma unroll
        for (int nt = 0; nt < 4; ++nt)
            #pragma unroll
            for (int r = 0; r < 4; ++r)
                Cw[(mt * 16 + q * 4 + r) * 64 + nt * 16 + ml] = f2bf(acc[mt][nt][r]);
    __syncthreads();
    #pragma unroll
    for (int it = 0; it < 8; ++it) {
        int task = it * 64 + lane;
        int grp = task & 7, row = task >> 3;
        size_t gr = m0 + wr * 64 + row;
        *(uint4*)&U[gr * 256 + j0 + wc * 64 + grp * 8] = *(const uint4*)&Cw[row * 64 + grp * 8];
    }
}

// ---------------- SRU scan (bf16 U in, bf16 h out, fp32 math) ----------------
__global__ __launch_bounds__(256) void k_scan(const u16* __restrict__ U,
                                              const float* __restrict__ v,
                                              const float* __restrict__ bbias,
                                              u16* __restrict__ hout, int layer) {
    const int G = 8;
    int d = blockIdx.y;
    int h = threadIdx.x & 31;
    int nl = threadIdx.x >> 5;
    int n = blockIdx.x * 8 + nl;
    const float* vv = v + (size_t)(layer * 2 + d) * 64;
    const float* bv = bbias + (size_t)(layer * 2 + d) * 64;
    float vf = vv[h], vr = vv[32 + h], bf_ = bv[h], br_ = bv[32 + h];
    const u16* Ub = U + (size_t)n * 256 + d * 128 + h;
    u16* Ho = hout + (size_t)n * 64 + d * 32 + h;
    const size_t stepU = (size_t)Nn * 256;
    const size_t stepH = (size_t)Nn * 64;
    int t0 = d ? (TnN - 1) : 0;
    int dt = d ? -1 : 1;
    float cz[G], cf[G], cr[G], cx[G];
    #pragma unroll
    for (int u = 0; u < G; u++) {
        const u16* p = Ub + (size_t)(t0 + dt * u) * stepU;
        cz[u] = bf2f(p[0]); cf[u] = bf2f(p[32]); cr[u] = bf2f(p[64]); cx[u] = bf2f(p[96]);
    }
    float c = 0.f;
    for (int g0 = 0; g0 < TnN; g0 += G) {
        float nz[G], nf[G], nr[G], nx[G];
        int g1 = g0 + G;
        #pragma unroll
        for (int u = 0; u < G; u++) {
            int g = g1 + u;
            if (g < TnN) {
                const u16* p = Ub + (size_t)(t0 + dt * g) * stepU;
                nz[u] = bf2f(p[0]); nf[u] = bf2f(p[32]); nr[u] = bf2f(p[64]); nx[u] = bf2f(p[96]);
            } else { nz[u] = 0.f; nf[u] = 0.f; nr[u] = 0.f; nx[u] = 0.f; }
        }
        #pragma unroll
        for (int u = 0; u < G; u++) {
            int g = g0 + u;
            if (g < TnN) {
                float fgate = 1.f / (1.f + __expf(-(cf[u] + vf * c + bf_)));
                float rgate = 1.f / (1.f + __expf(-(cr[u] + vr * c + br_)));
                c = fgate * c + (1.f - fgate) * cz[u];
                float hv = rgate * c + (1.f - rgate) * cx[u];
                Ho[(size_t)(t0 + dt * g) * stepH] = f2bf(hv);
            }
        }
        #pragma unroll
        for (int u = 0; u < G; u++) { cz[u] = nz[u]; cf[u] = nf[u]; cr[u] = nr[u]; cx[u] = nx[u]; }
    }
}

// ---------------- final conv via MFMA + bias + residual + transposed store ----------------
__global__ __launch_bounds__(256) void k_convm(const u16* __restrict__ hL,
                                               const u16* __restrict__ Wc,   // [64][512]
                                               const float* __restrict__ bct,
                                               const float* __restrict__ x,
                                               float* __restrict__ out) {
    __shared__ u16 As[128 * 40];
    __shared__ u16 Bs[64 * 40];
    const int tid = threadIdx.x;
    const int m0 = blockIdx.x * 128;
    const int t = m0 >> 8;
    const int n0 = m0 & 255;
    const int lane = tid & 63, w = tid >> 6;
    const int ml = lane & 15, q = lane >> 4;
    f32x4 acc[2][4] = {};
    for (int kc = 0; kc < 16; ++kc) {
        int c0 = kc * 32;
        int kk = kc >> 1;
        int ci0 = (kc & 1) * 32;
        int tau = t - kk;
        bool valid = (tau >= 0) && (tau < TnN);
        #pragma unroll
        for (int i = 0; i < 2; ++i) {
            int task = tid + i * 256;
            int row = task >> 2, grp = task & 3;
            uint4 val = make_uint4(0u, 0u, 0u, 0u);
            if (valid) val = *(const uint4*)&hL[((size_t)tau * 256 + n0 + row) * 64 + ci0 + grp * 8];
            *(uint4*)&As[row * 40 + grp * 8] = val;
        }
        {
            int o = tid >> 2, grp = tid & 3;
            *(uint4*)&Bs[o * 40 + grp * 8] = *(const uint4*)&Wc[o * 512 + c0 + grp * 8];
        }
        __syncthreads();
        bf16x8 af[2], bfv[4];
        #pragma unroll
        for (int mt = 0; mt < 2; ++mt) af[mt] = *(const bf16x8*)&As[(w * 32 + mt * 16 + ml) * 40 + q * 8];
        #pragma unroll
        for (int nt = 0; nt < 4; ++nt) bfv[nt] = *(const bf16x8*)&Bs[(nt * 16 + ml) * 40 + q * 8];
        #pragma unroll
        for (int mt = 0; mt < 2; ++mt)
            #pragma unroll
            for (int nt = 0; nt < 4; ++nt)
                acc[mt][nt] = __builtin_amdgcn_mfma_f32_16x16x32_bf16(af[mt], bfv[nt], acc[mt][nt], 0, 0, 0);
        __syncthreads();
    }
    float bc[4];
    #pragma unroll
    for (int nt = 0; nt < 4; ++nt) bc[nt] = bct[nt * 16 + ml];
    #pragma unroll
    for (int mt = 0; mt < 2; ++mt)
        #pragma unroll
        for (int r = 0; r < 4; ++r) {
            int n = n0 + w * 32 + mt * 16 + q * 4 + r;
            int b = n >> 7, f = n & 127;
            #pragma unroll
            for (int nt = 0; nt < 4; ++nt) {
                int o = nt * 16 + ml;
                size_t idx = ((size_t)(b * 64 + o) * 128 + f) * Tt + t;
                out[idx] = acc[mt][nt][r] + bc[nt] + x[idx];
            }
        }
}

extern "C" void kernel_launch(void* const* d_in, const int* in_sizes, int n_in,
                              void* d_out, int out_size, void* d_ws, size_t ws_size,
                              hipStream_t stream) {
    (void)in_sizes; (void)n_in; (void)out_size; (void)ws_size;
    const float* x     = (const float*)d_in[0];
    const float* gamma = (const float*)d_in[1];
    const float* beta  = (const float*)d_in[2];
    const float* W0    = (const float*)d_in[3];
    const float* Wr    = (const float*)d_in[4];
    const float* v     = (const float*)d_in[5];
    const float* bb    = (const float*)d_in[6];
    const float* wct   = (const float*)d_in[7];
    const float* bct   = (const float*)d_in[8];
    float* out = (float*)d_out;

    char* base = (char*)d_ws;
    float* stats = (float*)base;                         // 256 B
    u16* W0t  = (u16*)(base + 256);                      // 262144 B
    u16* Wrt  = (u16*)(base + 256 + 262144);             // 98304 B
    u16* Wcto = (u16*)(base + 256 + 262144 + 98304);     // 65536 B
    char* base2 = base + 426240;
    u16*  U  = (u16*)base2;                              // 62208*256*2 = 31,850,496 B
    float* xu = (float*)base2;                           // alias (dead after im2col): 16,777,216 B
    char* base3 = base2 + 31850496;
    u16* Abig = (u16*)base3;                             // 62208*512*2 = 63,700,992 B
    u16* h0   = (u16*)base3;                             // alias (Abig dead after gemm0)
    u16* h1   = (u16*)(base3 + 16 * 1024 * 1024);

    hipMemsetAsync(stats, 0, 32, stream);
    k_stats<<<dim3(128, 2), 256, 0, stream>>>(x, stats);
    k_norm<<<(Nn * 64 * Tt + 255) / 256, 256, 0, stream>>>(x, stats, gamma, beta, xu);
    k_packw<<<(212992 + 255) / 256, 256, 0, stream>>>(W0, Wr, wct, W0t, Wrt, Wcto);
    k_im2col<<<dim3(8, 32), 256, 0, stream>>>(xu, Abig);

    k_gemm0m<<<dim3(486, 2), 256, 0, stream>>>(Abig, W0t, U);
    k_scan<<<dim3(32, 2), 256, 0, stream>>>(U, v, bb, h0, 0);

    k_gemmr<<<dim3(486, 2), 256, 0, stream>>>(h0, Wrt, U);
    k_scan<<<dim3(32, 2), 256, 0, stream>>>(U, v, bb, h1, 1);

    k_gemmr<<<dim3(486, 2), 256, 0, stream>>>(h1, Wrt + 16384, U);
    k_scan<<<dim3(32, 2), 256, 0, stream>>>(U, v, bb, h0, 2);

    k_gemmr<<<dim3(486, 2), 256, 0, stream>>>(h0, Wrt + 32768, U);
    k_scan<<<dim3(32, 2), 256, 0, stream>>>(U, v, bb, h1, 3);

    k_convm<<<dim3(500), 256, 0, stream>>>(h1, Wcto, bct, x, out);
}

// Round 3
// 453.695 us; speedup vs baseline: 1.7933x; 1.4447x over previous
//
#include <hip/hip_runtime.h>
#include <math.h>

#define Tt 250
#define TnN 243
#define Nn 256
#define EPS_ 1e-5f

typedef unsigned short u16;
typedef __bf16 bf16x8 __attribute__((ext_vector_type(8)));
typedef float f32x4 __attribute__((ext_vector_type(4)));

__device__ __forceinline__ u16 f2bf(float f) {
    unsigned u = __builtin_bit_cast(unsigned, f);
    u += 0x7FFFu + ((u >> 16) & 1u);
    return (u16)(u >> 16);
}
__device__ __forceinline__ float bf2f(u16 s) {
    unsigned u = ((unsigned)s) << 16;
    return __builtin_bit_cast(float, u);
}

// ---------------- stats: per-batch sum & sumsq ----------------
__global__ void k_stats(const float* __restrict__ x, float* __restrict__ stats) {
    int b = blockIdx.y;
    const float* xb = x + (size_t)b * 64 * 128 * Tt;
    const int n = 64 * 128 * Tt;
    float s = 0.f, s2 = 0.f;
    for (int i = blockIdx.x * blockDim.x + threadIdx.x; i < n; i += gridDim.x * blockDim.x) {
        float v = xb[i];
        s += v; s2 += v * v;
    }
    for (int off = 32; off; off >>= 1) {
        s  += __shfl_down(s, off);
        s2 += __shfl_down(s2, off);
    }
    __shared__ float ls[8], ls2[8];
    int lane = threadIdx.x & 63, w = threadIdx.x >> 6;
    if (lane == 0) { ls[w] = s; ls2[w] = s2; }
    __syncthreads();
    if (threadIdx.x == 0) {
        float a = 0.f, a2 = 0.f;
        int nw = blockDim.x >> 6;
        for (int i = 0; i < nw; i++) { a += ls[i]; a2 += ls2[i]; }
        atomicAdd(&stats[b * 2 + 0], a);
        atomicAdd(&stats[b * 2 + 1], a2);
    }
}

// ---------------- normalize + write xu[n][c][t] (t padded to 256) ----------------
__global__ void k_norm(const float* __restrict__ x, const float* __restrict__ stats,
                       const float* __restrict__ gamma, const float* __restrict__ beta,
                       float* __restrict__ xu) {
    int idx = blockIdx.x * blockDim.x + threadIdx.x;
    const int total = Nn * 64 * Tt;
    if (idx >= total) return;
    int t = idx % Tt;
    int c = (idx / Tt) & 63;
    int n = idx / (Tt * 64);
    int b = n >> 7, f = n & 127;
    const float inv = 1.0f / (float)(64 * 128 * Tt);
    float mean = stats[b * 2 + 0] * inv;
    float var  = stats[b * 2 + 1] * inv - mean * mean;
    float rstd = rsqrtf(var + EPS_);
    float v = x[(((size_t)(b * 64 + c)) * 128 + f) * Tt + t];
    xu[((size_t)(n * 64 + c) << 8) + t] = (v - mean) * rstd * gamma[c] + beta[c];
}

// ---------------- pack all weights to bf16 (transposed to [out][k] layouts) ----------------
__global__ void k_packw(const float* __restrict__ W0, const float* __restrict__ Wr,
                        const float* __restrict__ wct,
                        u16* __restrict__ W0t, u16* __restrict__ Wrt, u16* __restrict__ Wcto) {
    int idx = blockIdx.x * blockDim.x + threadIdx.x;
    if (idx < 131072) {
        int j = idx >> 9, p = idx & 511;
        W0t[idx] = f2bf(W0[(size_t)(j >> 7) * 65536 + p * 128 + (j & 127)]);
    } else if (idx < 180224) {
        int r = idx - 131072;
        int i = r & 63, j = (r >> 6) & 255, lidx = r >> 14;
        Wrt[r] = f2bf(Wr[(size_t)(lidx * 2 + (j >> 7)) * 8192 + i * 128 + (j & 127)]);
    } else if (idx < 212992) {
        int r = idx - 180224;
        int o = r >> 9; int k = r & 511; int kk = k >> 6, ci = k & 63;
        Wcto[r] = f2bf(wct[(size_t)ci * 512 + o * 8 + kk]);
    }
}

// ---------------- im2col: Abig[t*256+n][c*8+kk] = bf16(xu[n][c][t+kk]) ----------------
__global__ __launch_bounds__(256) void k_im2col(const float* __restrict__ xu, u16* __restrict__ A) {
    __shared__ u16 lx[8][64][40];
    int t0 = blockIdx.x * 32;
    int n0 = blockIdx.y * 8;
    int tid = threadIdx.x;
    #pragma unroll
    for (int it = 0; it < 20; ++it) {
        int task = tid + it * 256;
        int v = task % 10;
        int c = (task / 10) & 63;
        int nn = task / 640;
        float4 f4 = *(const float4*)&xu[((size_t)((n0 + nn) * 64 + c) << 8) + t0 + v * 4];
        lx[nn][c][v * 4 + 0] = f2bf(f4.x);
        lx[nn][c][v * 4 + 1] = f2bf(f4.y);
        lx[nn][c][v * 4 + 2] = f2bf(f4.z);
        lx[nn][c][v * 4 + 3] = f2bf(f4.w);
    }
    __syncthreads();
    for (int it = 0; it < 64; ++it) {
        int task = it * 256 + tid;
        int c = task & 63, nn = (task >> 6) & 7, tt = task >> 9;
        int t = t0 + tt;
        if (t >= TnN) break;
        u16 tmp[8];
        #pragma unroll
        for (int j = 0; j < 8; ++j) tmp[j] = lx[nn][c][tt + j];
        uint4 o;
        o.x = (unsigned)tmp[0] | ((unsigned)tmp[1] << 16);
        o.y = (unsigned)tmp[2] | ((unsigned)tmp[3] << 16);
        o.z = (unsigned)tmp[4] | ((unsigned)tmp[5] << 16);
        o.w = (unsigned)tmp[6] | ((unsigned)tmp[7] << 16);
        *(uint4*)&A[((size_t)t * 256 + n0 + nn) * 512 + c * 8] = o;
    }
}

// ---------------- MFMA GEMM: U[m][j] = Abig[m][512] x W0t[j][512]^T, 128x128 tile ----------------
__global__ __launch_bounds__(256) void k_gemm0m(const u16* __restrict__ A,
                                                const u16* __restrict__ B,
                                                u16* __restrict__ U) {
    __shared__ u16 sh[16384];
    u16* As = sh;
    u16* Bs = sh + 5120;
    const int tid = threadIdx.x;
    const size_t m0 = (size_t)blockIdx.x * 128;
    const int j0 = blockIdx.y * 128;
    const int lane = tid & 63, w = tid >> 6;
    const int wr = w >> 1, wc = w & 1;
    const int ml = lane & 15, q = lane >> 4;
    f32x4 acc[4][4] = {};
    for (int kc = 0; kc < 16; ++kc) {
        int c0 = kc * 32;
        #pragma unroll
        for (int i = 0; i < 2; ++i) {
            int task = tid + i * 256;
            int row = task >> 2, grp = task & 3;
            *(uint4*)&As[row * 40 + grp * 8] = *(const uint4*)&A[(m0 + row) * 512 + c0 + grp * 8];
            *(uint4*)&Bs[row * 40 + grp * 8] = *(const uint4*)&B[(size_t)(j0 + row) * 512 + c0 + grp * 8];
        }
        __syncthreads();
        bf16x8 af[4], bfv[4];
        #pragma unroll
        for (int mt = 0; mt < 4; ++mt) af[mt] = *(const bf16x8*)&As[(wr * 64 + mt * 16 + ml) * 40 + q * 8];
        #pragma unroll
        for (int nt = 0; nt < 4; ++nt) bfv[nt] = *(const bf16x8*)&Bs[(wc * 64 + nt * 16 + ml) * 40 + q * 8];
        #pragma unroll
        for (int mt = 0; mt < 4; ++mt)
            #pragma unroll
            for (int nt = 0; nt < 4; ++nt)
                acc[mt][nt] = __builtin_amdgcn_mfma_f32_16x16x32_bf16(af[mt], bfv[nt], acc[mt][nt], 0, 0, 0);
        __syncthreads();
    }
    u16* Cw = sh + w * 4096;
    #pragma unroll
    for (int mt = 0; mt < 4; ++mt)
        #pragma unroll
        for (int nt = 0; nt < 4; ++nt)
            #pragma unroll
            for (int r = 0; r < 4; ++r)
                Cw[(mt * 16 + q * 4 + r) * 64 + nt * 16 + ml] = f2bf(acc[mt][nt][r]);
    __syncthreads();
    #pragma unroll
    for (int it = 0; it < 8; ++it) {
        int task = it * 64 + lane;
        int grp = task & 7, row = task >> 3;
        size_t gr = m0 + wr * 64 + row;
        *(uint4*)&U[gr * 256 + j0 + wc * 64 + grp * 8] = *(const uint4*)&Cw[row * 64 + grp * 8];
    }
}

// ---------------- MFMA GEMM layers 1..3: U[m][j] = h[m][64] x Wt[j][64]^T ----------------
__global__ __launch_bounds__(256) void k_gemmr(const u16* __restrict__ h,
                                               const u16* __restrict__ Wt,
                                               u16* __restrict__ U) {
    __shared__ u16 sh[16384];
    u16* As = sh;
    u16* Bs = sh + 5120;
    const int tid = threadIdx.x;
    const size_t m0 = (size_t)blockIdx.x * 128;
    const int j0 = blockIdx.y * 128;
    const int lane = tid & 63, w = tid >> 6;
    const int wr = w >> 1, wc = w & 1;
    const int ml = lane & 15, q = lane >> 4;
    f32x4 acc[4][4] = {};
    for (int kc = 0; kc < 2; ++kc) {
        int c0 = kc * 32;
        #pragma unroll
        for (int i = 0; i < 2; ++i) {
            int task = tid + i * 256;
            int row = task >> 2, grp = task & 3;
            *(uint4*)&As[row * 40 + grp * 8] = *(const uint4*)&h[(m0 + row) * 64 + c0 + grp * 8];
            *(uint4*)&Bs[row * 40 + grp * 8] = *(const uint4*)&Wt[(size_t)(j0 + row) * 64 + c0 + grp * 8];
        }
        __syncthreads();
        bf16x8 af[4], bfv[4];
        #pragma unroll
        for (int mt = 0; mt < 4; ++mt) af[mt] = *(const bf16x8*)&As[(wr * 64 + mt * 16 + ml) * 40 + q * 8];
        #pragma unroll
        for (int nt = 0; nt < 4; ++nt) bfv[nt] = *(const bf16x8*)&Bs[(wc * 64 + nt * 16 + ml) * 40 + q * 8];
        #pragma unroll
        for (int mt = 0; mt < 4; ++mt)
            #pragma unroll
            for (int nt = 0; nt < 4; ++nt)
                acc[mt][nt] = __builtin_amdgcn_mfma_f32_16x16x32_bf16(af[mt], bfv[nt], acc[mt][nt], 0, 0, 0);
        __syncthreads();
    }
    u16* Cw = sh + w * 4096;
    #pragma unroll
    for (int mt = 0; mt < 4; ++mt)
        #pragma unroll
        for (int nt = 0; nt < 4; ++nt)
            #pragma unroll
            for (int r = 0; r < 4; ++r)
                Cw[(mt * 16 + q * 4 + r) * 64 + nt * 16 + ml] = f2bf(acc[mt][nt][r]);
    __syncthreads();
    #pragma unroll
    for (int it = 0; it < 8; ++it) {
        int task = it * 64 + lane;
        int grp = task & 7, row = task >> 3;
        size_t gr = m0 + wr * 64 + row;
        *(uint4*)&U[gr * 256 + j0 + wc * 64 + grp * 8] = *(const uint4*)&Cw[row * 64 + grp * 8];
    }
}

// ---------------- SRU scan: wave-synchronous, LDS-staged, double-buffered ----------------
// block = 64 threads (one wave) = 2 n x 32 h, one direction. grid = (128, 2).
__global__ __launch_bounds__(64) void k_scan(const u16* __restrict__ U,
                                             const float* __restrict__ v,
                                             const float* __restrict__ bbias,
                                             u16* __restrict__ hout, int layer) {
    // LDS: 2 buffers x 16 rows (tt*2+n) x 160 u16 (128 data + 32 pad -> n-stride = bank+16)
    __shared__ u16 lds[2][16 * 160];
    const int lane = threadIdx.x;
    const int d = blockIdx.y;
    const int n0 = blockIdx.x * 2;
    const int h = lane & 31, nl = lane >> 5;
    const float* vv = v + (size_t)(layer * 2 + d) * 64;
    const float* bv = bbias + (size_t)(layer * 2 + d) * 64;
    const float vf = vv[h], vr = vv[32 + h], bf_ = bv[h], br_ = bv[32 + h];
    const int t0 = d ? (TnN - 1) : 0;
    const int dt = d ? -1 : 1;
    // per-thread load slots: u4 = it*64+lane -> tt = u4>>5, nn = (u4>>4)&1, grp = u4&15
    const int l_tt[4]  = { lane >> 5, (64 + lane) >> 5, (128 + lane) >> 5, (192 + lane) >> 5 };
    const int l_nn = (lane >> 4) & 1;
    const int l_grp = lane & 15;
    uint4 pre[4];

    #pragma unroll
    for (int it = 0; it < 4; ++it) {
        int g = l_tt[it];
        int t = t0 + dt * g;
        pre[it] = *(const uint4*)&U[((size_t)t * 256 + n0 + l_nn) * 256 + d * 128 + l_grp * 8];
    }
    #pragma unroll
    for (int it = 0; it < 4; ++it)
        *(uint4*)&lds[0][(l_tt[it] * 2 + l_nn) * 160 + l_grp * 8] = pre[it];
    __syncthreads();

    float c = 0.f;
    for (int g0 = 0; g0 < TnN; g0 += 8) {
        const int buf = (g0 >> 3) & 1;
        const bool more = (g0 + 8) < TnN;
        if (more) {
            #pragma unroll
            for (int it = 0; it < 4; ++it) {
                int g = g0 + 8 + l_tt[it];
                int gc = g < TnN ? g : (TnN - 1);
                int t = t0 + dt * gc;
                pre[it] = *(const uint4*)&U[((size_t)t * 256 + n0 + l_nn) * 256 + d * 128 + l_grp * 8];
            }
        }
        // gather this group's gates from LDS
        float gz[8], gf[8], gr_[8], gx[8];
        #pragma unroll
        for (int u = 0; u < 8; ++u) {
            const u16* row = &lds[buf][(u * 2 + nl) * 160];
            gz[u] = bf2f(row[h]);
            gf[u] = bf2f(row[32 + h]);
            gr_[u] = bf2f(row[64 + h]);
            gx[u] = bf2f(row[96 + h]);
        }
        #pragma unroll
        for (int u = 0; u < 8; ++u) {
            int g = g0 + u;
            if (g < TnN) {
                float fg = 1.f / (1.f + __expf(-(gf[u] + vf * c + bf_)));
                float rg = 1.f / (1.f + __expf(-(gr_[u] + vr * c + br_)));
                c = fg * c + (1.f - fg) * gz[u];
                float hv = rg * c + (1.f - rg) * gx[u];
                int t = t0 + dt * g;
                hout[(size_t)t * 16384 + (size_t)(n0 + nl) * 64 + d * 32 + h] = f2bf(hv);
            }
        }
        if (more) {
            #pragma unroll
            for (int it = 0; it < 4; ++it)
                *(uint4*)&lds[buf ^ 1][(l_tt[it] * 2 + l_nn) * 160 + l_grp * 8] = pre[it];
        }
        __syncthreads();
    }
}

// ---------------- final conv via MFMA + bias + residual + transposed store ----------------
__global__ __launch_bounds__(256) void k_convm(const u16* __restrict__ hL,
                                               const u16* __restrict__ Wc,   // [64][512]
                                               const float* __restrict__ bct,
                                               const float* __restrict__ x,
                                               float* __restrict__ out) {
    __shared__ u16 As[128 * 40];
    __shared__ u16 Bs[64 * 40];
    const int tid = threadIdx.x;
    const int m0 = blockIdx.x * 128;
    const int t = m0 >> 8;
    const int n0 = m0 & 255;
    const int lane = tid & 63, w = tid >> 6;
    const int ml = lane & 15, q = lane >> 4;
    f32x4 acc[2][4] = {};
    for (int kc = 0; kc < 16; ++kc) {
        int c0 = kc * 32;
        int kk = kc >> 1;
        int ci0 = (kc & 1) * 32;
        int tau = t - kk;
        bool valid = (tau >= 0) && (tau < TnN);
        #pragma unroll
        for (int i = 0; i < 2; ++i) {
            int task = tid + i * 256;
            int row = task >> 2, grp = task & 3;
            uint4 val = make_uint4(0u, 0u, 0u, 0u);
            if (valid) val = *(const uint4*)&hL[((size_t)tau * 256 + n0 + row) * 64 + ci0 + grp * 8];
            *(uint4*)&As[row * 40 + grp * 8] = val;
        }
        {
            int o = tid >> 2, grp = tid & 3;
            *(uint4*)&Bs[o * 40 + grp * 8] = *(const uint4*)&Wc[o * 512 + c0 + grp * 8];
        }
        __syncthreads();
        bf16x8 af[2], bfv[4];
        #pragma unroll
        for (int mt = 0; mt < 2; ++mt) af[mt] = *(const bf16x8*)&As[(w * 32 + mt * 16 + ml) * 40 + q * 8];
        #pragma unroll
        for (int nt = 0; nt < 4; ++nt) bfv[nt] = *(const bf16x8*)&Bs[(nt * 16 + ml) * 40 + q * 8];
        #pragma unroll
        for (int mt = 0; mt < 2; ++mt)
            #pragma unroll
            for (int nt = 0; nt < 4; ++nt)
                acc[mt][nt] = __builtin_amdgcn_mfma_f32_16x16x32_bf16(af[mt], bfv[nt], acc[mt][nt], 0, 0, 0);
        __syncthreads();
    }
    float bc[4];
    #pragma unroll
    for (int nt = 0; nt < 4; ++nt) bc[nt] = bct[nt * 16 + ml];
    #pragma unroll
    for (int mt = 0; mt < 2; ++mt)
        #pragma unroll
        for (int r = 0; r < 4; ++r) {
            int n = n0 + w * 32 + mt * 16 + q * 4 + r;
            int b = n >> 7, f = n & 127;
            #pragma unroll
            for (int nt = 0; nt < 4; ++nt) {
                int o = nt * 16 + ml;
                size_t idx = ((size_t)(b * 64 + o) * 128 + f) * Tt + t;
                out[idx] = acc[mt][nt][r] + bc[nt] + x[idx];
            }
        }
}

extern "C" void kernel_launch(void* const* d_in, const int* in_sizes, int n_in,
                              void* d_out, int out_size, void* d_ws, size_t ws_size,
                              hipStream_t stream) {
    (void)in_sizes; (void)n_in; (void)out_size; (void)ws_size;
    const float* x     = (const float*)d_in[0];
    const float* gamma = (const float*)d_in[1];
    const float* beta  = (const float*)d_in[2];
    const float* W0    = (const float*)d_in[3];
    const float* Wr    = (const float*)d_in[4];
    const float* v     = (const float*)d_in[5];
    const float* bb    = (const float*)d_in[6];
    const float* wct   = (const float*)d_in[7];
    const float* bct   = (const float*)d_in[8];
    float* out = (float*)d_out;

    char* base = (char*)d_ws;
    float* stats = (float*)base;
    u16* W0t  = (u16*)(base + 256);
    u16* Wrt  = (u16*)(base + 256 + 262144);
    u16* Wcto = (u16*)(base + 256 + 262144 + 98304);
    char* base2 = base + 426240;
    u16*  U  = (u16*)base2;                              // 31,850,496 B
    float* xu = (float*)base2;                           // alias (dead after im2col)
    char* base3 = base2 + 31850496;
    u16* Abig = (u16*)base3;                             // 63,700,992 B
    u16* h0   = (u16*)base3;                             // alias (Abig dead after gemm0)
    u16* h1   = (u16*)(base3 + 16 * 1024 * 1024);

    hipMemsetAsync(stats, 0, 32, stream);
    k_stats<<<dim3(128, 2), 256, 0, stream>>>(x, stats);
    k_norm<<<(Nn * 64 * Tt + 255) / 256, 256, 0, stream>>>(x, stats, gamma, beta, xu);
    k_packw<<<(212992 + 255) / 256, 256, 0, stream>>>(W0, Wr, wct, W0t, Wrt, Wcto);
    k_im2col<<<dim3(8, 32), 256, 0, stream>>>(xu, Abig);

    k_gemm0m<<<dim3(486, 2), 256, 0, stream>>>(Abig, W0t, U);
    k_scan<<<dim3(128, 2), 64, 0, stream>>>(U, v, bb, h0, 0);

    k_gemmr<<<dim3(486, 2), 256, 0, stream>>>(h0, Wrt, U);
    k_scan<<<dim3(128, 2), 64, 0, stream>>>(U, v, bb, h1, 1);

    k_gemmr<<<dim3(486, 2), 256, 0, stream>>>(h1, Wrt + 16384, U);
    k_scan<<<dim3(128, 2), 64, 0, stream>>>(U, v, bb, h0, 2);

    k_gemmr<<<dim3(486, 2), 256, 0, stream>>>(h0, Wrt + 32768, U);
    k_scan<<<dim3(128, 2), 64, 0, stream>>>(U, v, bb, h1, 3);

    k_convm<<<dim3(500), 256, 0, stream>>>(h1, Wcto, bct, x, out);
}

// Round 5
// 372.555 us; speedup vs baseline: 2.1839x; 1.2178x over previous
//
#include <hip/hip_runtime.h>
#include <math.h>

#define Tt 250
#define TnN 243
#define Nn 256
#define EPS_ 1e-5f

typedef unsigned short u16;
typedef __bf16 bf16x8 __attribute__((ext_vector_type(8)));
typedef float f32x4 __attribute__((ext_vector_type(4)));

__device__ __forceinline__ u16 f2bf(float f) {
    unsigned u = __builtin_bit_cast(unsigned, f);
    u += 0x7FFFu + ((u >> 16) & 1u);
    return (u16)(u >> 16);
}
__device__ __forceinline__ float bf2f(u16 s) {
    unsigned u = ((unsigned)s) << 16;
    return __builtin_bit_cast(float, u);
}

// ---------------- stats: per-batch sum & sumsq ----------------
__global__ void k_stats(const float* __restrict__ x, float* __restrict__ stats) {
    int b = blockIdx.y;
    const float* xb = x + (size_t)b * 64 * 128 * Tt;
    const int n = 64 * 128 * Tt;
    float s = 0.f, s2 = 0.f;
    for (int i = blockIdx.x * blockDim.x + threadIdx.x; i < n; i += gridDim.x * blockDim.x) {
        float v = xb[i];
        s += v; s2 += v * v;
    }
    for (int off = 32; off; off >>= 1) {
        s  += __shfl_down(s, off);
        s2 += __shfl_down(s2, off);
    }
    __shared__ float ls[8], ls2[8];
    int lane = threadIdx.x & 63, w = threadIdx.x >> 6;
    if (lane == 0) { ls[w] = s; ls2[w] = s2; }
    __syncthreads();
    if (threadIdx.x == 0) {
        float a = 0.f, a2 = 0.f;
        int nw = blockDim.x >> 6;
        for (int i = 0; i < nw; i++) { a += ls[i]; a2 += ls2[i]; }
        atomicAdd(&stats[b * 2 + 0], a);
        atomicAdd(&stats[b * 2 + 1], a2);
    }
}

// ---------------- normalize + write xu[n][c][t] (t padded to 256) ----------------
__global__ void k_norm(const float* __restrict__ x, const float* __restrict__ stats,
                       const float* __restrict__ gamma, const float* __restrict__ beta,
                       float* __restrict__ xu) {
    int idx = blockIdx.x * blockDim.x + threadIdx.x;
    const int total = Nn * 64 * Tt;
    if (idx >= total) return;
    int t = idx % Tt;
    int c = (idx / Tt) & 63;
    int n = idx / (Tt * 64);
    int b = n >> 7, f = n & 127;
    const float inv = 1.0f / (float)(64 * 128 * Tt);
    float mean = stats[b * 2 + 0] * inv;
    float var  = stats[b * 2 + 1] * inv - mean * mean;
    float rstd = rsqrtf(var + EPS_);
    float v = x[(((size_t)(b * 64 + c)) * 128 + f) * Tt + t];
    xu[((size_t)(n * 64 + c) << 8) + t] = (v - mean) * rstd * gamma[c] + beta[c];
}

// ---------------- pack all weights to bf16 (transposed to [out][k] layouts) ----------------
__global__ void k_packw(const float* __restrict__ W0, const float* __restrict__ Wr,
                        const float* __restrict__ wct,
                        u16* __restrict__ W0t, u16* __restrict__ Wrt, u16* __restrict__ Wcto) {
    int idx = blockIdx.x * blockDim.x + threadIdx.x;
    if (idx < 131072) {
        int j = idx >> 9, p = idx & 511;
        W0t[idx] = f2bf(W0[(size_t)(j >> 7) * 65536 + p * 128 + (j & 127)]);
    } else if (idx < 180224) {
        int r = idx - 131072;
        int i = r & 63, j = (r >> 6) & 255, lidx = r >> 14;
        Wrt[r] = f2bf(Wr[(size_t)(lidx * 2 + (j >> 7)) * 8192 + i * 128 + (j & 127)]);
    } else if (idx < 212992) {
        int r = idx - 180224;
        int o = r >> 9; int k = r & 511; int kk = k >> 6, ci = k & 63;
        Wcto[r] = f2bf(wct[(size_t)ci * 512 + o * 8 + kk]);
    }
}

// ---------------- im2col: Abig[t*256+n][c*8+kk] = bf16(xu[n][c][t+kk]) ----------------
__global__ __launch_bounds__(256) void k_im2col(const float* __restrict__ xu, u16* __restrict__ A) {
    __shared__ u16 lx[8][64][40];
    int t0 = blockIdx.x * 32;
    int n0 = blockIdx.y * 8;
    int tid = threadIdx.x;
    #pragma unroll
    for (int it = 0; it < 20; ++it) {
        int task = tid + it * 256;
        int v = task % 10;
        int c = (task / 10) & 63;
        int nn = task / 640;
        float4 f4 = *(const float4*)&xu[((size_t)((n0 + nn) * 64 + c) << 8) + t0 + v * 4];
        lx[nn][c][v * 4 + 0] = f2bf(f4.x);
        lx[nn][c][v * 4 + 1] = f2bf(f4.y);
        lx[nn][c][v * 4 + 2] = f2bf(f4.z);
        lx[nn][c][v * 4 + 3] = f2bf(f4.w);
    }
    __syncthreads();
    for (int it = 0; it < 64; ++it) {
        int task = it * 256 + tid;
        int c = task & 63, nn = (task >> 6) & 7, tt = task >> 9;
        int t = t0 + tt;
        if (t >= TnN) break;
        u16 tmp[8];
        #pragma unroll
        for (int j = 0; j < 8; ++j) tmp[j] = lx[nn][c][tt + j];
        uint4 o;
        o.x = (unsigned)tmp[0] | ((unsigned)tmp[1] << 16);
        o.y = (unsigned)tmp[2] | ((unsigned)tmp[3] << 16);
        o.z = (unsigned)tmp[4] | ((unsigned)tmp[5] << 16);
        o.w = (unsigned)tmp[6] | ((unsigned)tmp[7] << 16);
        *(uint4*)&A[((size_t)t * 256 + n0 + nn) * 512 + c * 8] = o;
    }
}

// ---------------- MFMA GEMM: U[m][j] = Abig[m][512] x W0t[j][512]^T, 128x128 tile ----------------
__global__ __launch_bounds__(256) void k_gemm0m(const u16* __restrict__ A,
                                                const u16* __restrict__ B,
                                                u16* __restrict__ U) {
    __shared__ u16 sh[16384];
    u16* As = sh;
    u16* Bs = sh + 5120;
    const int tid = threadIdx.x;
    const size_t m0 = (size_t)blockIdx.x * 128;
    const int j0 = blockIdx.y * 128;
    const int lane = tid & 63, w = tid >> 6;
    const int wr = w >> 1, wc = w & 1;
    const int ml = lane & 15, q = lane >> 4;
    f32x4 acc[4][4] = {};
    for (int kc = 0; kc < 16; ++kc) {
        int c0 = kc * 32;
        #pragma unroll
        for (int i = 0; i < 2; ++i) {
            int task = tid + i * 256;
            int row = task >> 2, grp = task & 3;
            *(uint4*)&As[row * 40 + grp * 8] = *(const uint4*)&A[(m0 + row) * 512 + c0 + grp * 8];
            *(uint4*)&Bs[row * 40 + grp * 8] = *(const uint4*)&B[(size_t)(j0 + row) * 512 + c0 + grp * 8];
        }
        __syncthreads();
        bf16x8 af[4], bfv[4];
        #pragma unroll
        for (int mt = 0; mt < 4; ++mt) af[mt] = *(const bf16x8*)&As[(wr * 64 + mt * 16 + ml) * 40 + q * 8];
        #pragma unroll
        for (int nt = 0; nt < 4; ++nt) bfv[nt] = *(const bf16x8*)&Bs[(wc * 64 + nt * 16 + ml) * 40 + q * 8];
        #pragma unroll
        for (int mt = 0; mt < 4; ++mt)
            #pragma unroll
            for (int nt = 0; nt < 4; ++nt)
                acc[mt][nt] = __builtin_amdgcn_mfma_f32_16x16x32_bf16(af[mt], bfv[nt], acc[mt][nt], 0, 0, 0);
        __syncthreads();
    }
    u16* Cw = sh + w * 4096;
    #pragma unroll
    for (int mt = 0; mt < 4; ++mt)
        #pragma unroll
        for (int nt = 0; nt < 4; ++nt)
            #pragma unroll
            for (int r = 0; r < 4; ++r)
                Cw[(mt * 16 + q * 4 + r) * 64 + nt * 16 + ml] = f2bf(acc[mt][nt][r]);
    __syncthreads();
    #pragma unroll
    for (int it = 0; it < 8; ++it) {
        int task = it * 64 + lane;
        int grp = task & 7, row = task >> 3;
        size_t gr = m0 + wr * 64 + row;
        *(uint4*)&U[gr * 256 + j0 + wc * 64 + grp * 8] = *(const uint4*)&Cw[row * 64 + grp * 8];
    }
}

// ---------------- SRU scan layer 0 (global U) ----------------
__global__ __launch_bounds__(64) void k_scan(const u16* __restrict__ U,
                                             const float* __restrict__ v,
                                             const float* __restrict__ bbias,
                                             u16* __restrict__ hout, int layer) {
    __shared__ u16 lds[2][16 * 160];
    const int lane = threadIdx.x;
    const int d = blockIdx.y;
    const int n0 = blockIdx.x * 2;
    const int h = lane & 31, nl = lane >> 5;
    const float* vv = v + (size_t)(layer * 2 + d) * 64;
    const float* bv = bbias + (size_t)(layer * 2 + d) * 64;
    const float vf = vv[h], vr = vv[32 + h], bf_ = bv[h], br_ = bv[32 + h];
    const int t0 = d ? (TnN - 1) : 0;
    const int dt = d ? -1 : 1;
    const int l_tt[4]  = { lane >> 5, (64 + lane) >> 5, (128 + lane) >> 5, (192 + lane) >> 5 };
    const int l_nn = (lane >> 4) & 1;
    const int l_grp = lane & 15;
    uint4 pre[4];

    #pragma unroll
    for (int it = 0; it < 4; ++it) {
        int g = l_tt[it];
        int t = t0 + dt * g;
        pre[it] = *(const uint4*)&U[((size_t)t * 256 + n0 + l_nn) * 256 + d * 128 + l_grp * 8];
    }
    #pragma unroll
    for (int it = 0; it < 4; ++it)
        *(uint4*)&lds[0][(l_tt[it] * 2 + l_nn) * 160 + l_grp * 8] = pre[it];
    __syncthreads();

    float c = 0.f;
    for (int g0 = 0; g0 < TnN; g0 += 8) {
        const int buf = (g0 >> 3) & 1;
        const bool more = (g0 + 8) < TnN;
        if (more) {
            #pragma unroll
            for (int it = 0; it < 4; ++it) {
                int g = g0 + 8 + l_tt[it];
                int gc = g < TnN ? g : (TnN - 1);
                int t = t0 + dt * gc;
                pre[it] = *(const uint4*)&U[((size_t)t * 256 + n0 + l_nn) * 256 + d * 128 + l_grp * 8];
            }
        }
        float gz[8], gf[8], gr_[8], gx[8];
        #pragma unroll
        for (int u = 0; u < 8; ++u) {
            const u16* row = &lds[buf][(u * 2 + nl) * 160];
            gz[u] = bf2f(row[h]);
            gf[u] = bf2f(row[32 + h]);
            gr_[u] = bf2f(row[64 + h]);
            gx[u] = bf2f(row[96 + h]);
        }
        #pragma unroll
        for (int u = 0; u < 8; ++u) {
            int g = g0 + u;
            if (g < TnN) {
                float fg = 1.f / (1.f + __expf(-(gf[u] + vf * c + bf_)));
                float rg = 1.f / (1.f + __expf(-(gr_[u] + vr * c + br_)));
                c = fg * c + (1.f - fg) * gz[u];
                float hv = rg * c + (1.f - rg) * gx[u];
                int t = t0 + dt * g;
                hout[(size_t)t * 16384 + (size_t)(n0 + nl) * 64 + d * 32 + h] = f2bf(hv);
            }
        }
        if (more) {
            #pragma unroll
            for (int it = 0; it < 4; ++it)
                *(uint4*)&lds[buf ^ 1][(l_tt[it] * 2 + l_nn) * 160 + l_grp * 8] = pre[it];
        }
        __syncthreads();
    }
}

// ---------------- fused layer (1..3): GEMM (K=64) + scan, one block per (n, d) ----------------
// LDS union: phase1 A(256x72) + B(128x72) = 55296 B; phase2 U(243x132) = 64152 B
__global__ __launch_bounds__(256) void k_layer(const u16* __restrict__ hin,
                                               const u16* __restrict__ Wrt_l, // [256 j][64 i]
                                               const float* __restrict__ v,
                                               const float* __restrict__ bbias,
                                               u16* __restrict__ hout, int layer) {
    __shared__ u16 sh[32768];   // 64 KiB
    u16* Ah = sh;               // 256 rows x 72
    u16* Bs = sh + 256 * 72;    // 128 rows x 72
    const int tid = threadIdx.x;
    const int n = blockIdx.x, d = blockIdx.y;
    #pragma unroll
    for (int it = 0; it < 8; ++it) {
        int task = it * 256 + tid;
        int row = task >> 3, grp = task & 7;
        if (row < TnN)
            *(uint4*)&Ah[row * 72 + grp * 8] = *(const uint4*)&hin[((size_t)row * 256 + n) * 64 + grp * 8];
        else if (row < 256)
            *(uint4*)&Ah[row * 72 + grp * 8] = make_uint4(0, 0, 0, 0);
    }
    #pragma unroll
    for (int it = 0; it < 4; ++it) {
        int task = it * 256 + tid;
        int j = task >> 3, grp = task & 7;
        *(uint4*)&Bs[j * 72 + grp * 8] = *(const uint4*)&Wrt_l[((size_t)(d * 128 + j)) * 64 + grp * 8];
    }
    __syncthreads();
    const int lane = tid & 63, w = tid >> 6;
    const int ml = lane & 15, q = lane >> 4;
    f32x4 acc[4][8] = {};
    #pragma unroll
    for (int c2 = 0; c2 < 2; ++c2) {
        int c0 = c2 * 32;
        bf16x8 af[4];
        #pragma unroll
        for (int mt = 0; mt < 4; ++mt)
            af[mt] = *(const bf16x8*)&Ah[(w * 64 + mt * 16 + ml) * 72 + c0 + q * 8];
        #pragma unroll
        for (int nt = 0; nt < 8; ++nt) {
            bf16x8 bfr = *(const bf16x8*)&Bs[(nt * 16 + ml) * 72 + c0 + q * 8];
            #pragma unroll
            for (int mt = 0; mt < 4; ++mt)
                acc[mt][nt] = __builtin_amdgcn_mfma_f32_16x16x32_bf16(af[mt], bfr, acc[mt][nt], 0, 0, 0);
        }
    }
    __syncthreads();
    u16* Ul = sh;               // 243 rows x 132
    #pragma unroll
    for (int mt = 0; mt < 4; ++mt)
        #pragma unroll
        for (int r = 0; r < 4; ++r) {
            int t = w * 64 + mt * 16 + q * 4 + r;
            if (t < TnN) {
                #pragma unroll
                for (int nt = 0; nt < 8; ++nt)
                    Ul[t * 132 + nt * 16 + ml] = f2bf(acc[mt][nt][r]);
            }
        }
    __syncthreads();
    if (tid >= 32) return;
    const int h = tid;
    const float* vv = v + (size_t)(layer * 2 + d) * 64;
    const float* bv = bbias + (size_t)(layer * 2 + d) * 64;
    const float vf = vv[h], vr = vv[32 + h], bf_ = bv[h], br_ = bv[32 + h];
    const int t0 = d ? (TnN - 1) : 0;
    const int dt = d ? -1 : 1;
    float c = 0.f;
    for (int g0 = 0; g0 < TnN; g0 += 8) {
        float gz[8], gf[8], gr_[8], gx[8];
        #pragma unroll
        for (int u = 0; u < 8; ++u) {
            int g = g0 + u; int gg = g < TnN ? g : (TnN - 1);
            int t = t0 + dt * gg;
            const u16* row = &Ul[t * 132];
            gz[u] = bf2f(row[h]); gf[u] = bf2f(row[32 + h]);
            gr_[u] = bf2f(row[64 + h]); gx[u] = bf2f(row[96 + h]);
        }
        #pragma unroll
        for (int u = 0; u < 8; ++u) {
            int g = g0 + u;
            if (g < TnN) {
                float fg = 1.f / (1.f + __expf(-(gf[u] + vf * c + bf_)));
                float rg = 1.f / (1.f + __expf(-(gr_[u] + vr * c + br_)));
                c = fg * c + (1.f - fg) * gz[u];
                float hv = rg * c + (1.f - rg) * gx[u];
                int t = t0 + dt * g;
                hout[(size_t)t * 16384 + (size_t)n * 64 + d * 32 + h] = f2bf(hv);
            }
        }
    }
}

// ---------------- final conv per-n block: MFMA + bias + residual ----------------
__global__ __launch_bounds__(256) void k_convm(const u16* __restrict__ hL,
                                               const u16* __restrict__ Wc,   // [64 o][512 k]
                                               const float* __restrict__ bct,
                                               const float* __restrict__ x,
                                               float* __restrict__ out) {
    __shared__ u16 As[264 * 72];   // rows: tau+7 for tau in [-7..256]; guards zeroed
    __shared__ u16 Bs[64 * 40];
    const int tid = threadIdx.x;
    const int n = blockIdx.x;
    const int b = n >> 7, f = n & 127;
    #pragma unroll
    for (int it = 0; it < 8; ++it) {
        int task = it * 256 + tid;
        int row = task >> 3, grp = task & 7;
        if (row < TnN)
            *(uint4*)&As[(row + 7) * 72 + grp * 8] = *(const uint4*)&hL[((size_t)row * 256 + n) * 64 + grp * 8];
    }
    if (tid < 168) {               // zero guards: rows 0..6 and 250..263
        int r = tid >> 3, grp = tid & 7;
        int row = r < 7 ? r : (TnN + r);
        *(uint4*)&As[row * 72 + grp * 8] = make_uint4(0, 0, 0, 0);
    }
    const int lane = tid & 63, w = tid >> 6;
    const int ml = lane & 15, q = lane >> 4;
    f32x4 acc[4][4] = {};
    for (int kc = 0; kc < 16; ++kc) {
        int kk = kc >> 1, ci0 = (kc & 1) * 32;
        {
            // all 256 threads: o = tid>>2 (0..63), grp = tid&3 (0..3) -> full 32 columns
            int o = tid >> 2, grp = tid & 3;
            *(uint4*)&Bs[o * 40 + grp * 8] = *(const uint4*)&Wc[(size_t)o * 512 + kc * 32 + grp * 8];
        }
        __syncthreads();
        bf16x8 af[4], bfv[4];
        #pragma unroll
        for (int mt = 0; mt < 4; ++mt)
            af[mt] = *(const bf16x8*)&As[(w * 64 + mt * 16 + ml - kk + 7) * 72 + ci0 + q * 8];
        #pragma unroll
        for (int nt = 0; nt < 4; ++nt)
            bfv[nt] = *(const bf16x8*)&Bs[(nt * 16 + ml) * 40 + q * 8];
        #pragma unroll
        for (int mt = 0; mt < 4; ++mt)
            #pragma unroll
            for (int nt = 0; nt < 4; ++nt)
                acc[mt][nt] = __builtin_amdgcn_mfma_f32_16x16x32_bf16(af[mt], bfv[nt], acc[mt][nt], 0, 0, 0);
        __syncthreads();
    }
    float bc[4];
    #pragma unroll
    for (int nt = 0; nt < 4; ++nt) bc[nt] = bct[nt * 16 + ml];
    #pragma unroll
    for (int mt = 0; mt < 4; ++mt)
        #pragma unroll
        for (int r = 0; r < 4; ++r) {
            int t = w * 64 + mt * 16 + q * 4 + r;
            if (t < Tt) {
                #pragma unroll
                for (int nt = 0; nt < 4; ++nt) {
                    int o = nt * 16 + ml;
                    size_t idx = ((size_t)(b * 64 + o) * 128 + f) * Tt + t;
                    out[idx] = acc[mt][nt][r] + bc[nt] + x[idx];
                }
            }
        }
}

extern "C" void kernel_launch(void* const* d_in, const int* in_sizes, int n_in,
                              void* d_out, int out_size, void* d_ws, size_t ws_size,
                              hipStream_t stream) {
    (void)in_sizes; (void)n_in; (void)out_size; (void)ws_size;
    const float* x     = (const float*)d_in[0];
    const float* gamma = (const float*)d_in[1];
    const float* beta  = (const float*)d_in[2];
    const float* W0    = (const float*)d_in[3];
    const float* Wr    = (const float*)d_in[4];
    const float* v     = (const float*)d_in[5];
    const float* bb    = (const float*)d_in[6];
    const float* wct   = (const float*)d_in[7];
    const float* bct   = (const float*)d_in[8];
    float* out = (float*)d_out;

    char* base = (char*)d_ws;
    float* stats = (float*)base;
    u16* W0t  = (u16*)(base + 256);
    u16* Wrt  = (u16*)(base + 256 + 262144);
    u16* Wcto = (u16*)(base + 256 + 262144 + 98304);
    char* base2 = base + 426240;
    u16*  U  = (u16*)base2;                              // 31,850,496 B (layer-0 only)
    float* xu = (float*)base2;                           // alias (dead after im2col)
    char* base3 = base2 + 31850496;
    u16* Abig = (u16*)base3;                             // 63,700,992 B
    u16* h0   = (u16*)base3;                             // alias (Abig dead after gemm0m)
    u16* h1   = (u16*)(base3 + 16 * 1024 * 1024);

    hipMemsetAsync(stats, 0, 32, stream);
    k_stats<<<dim3(128, 2), 256, 0, stream>>>(x, stats);
    k_norm<<<(Nn * 64 * Tt + 255) / 256, 256, 0, stream>>>(x, stats, gamma, beta, xu);
    k_packw<<<(212992 + 255) / 256, 256, 0, stream>>>(W0, Wr, wct, W0t, Wrt, Wcto);
    k_im2col<<<dim3(8, 32), 256, 0, stream>>>(xu, Abig);

    k_gemm0m<<<dim3(486, 2), 256, 0, stream>>>(Abig, W0t, U);
    k_scan<<<dim3(128, 2), 64, 0, stream>>>(U, v, bb, h0, 0);

    k_layer<<<dim3(256, 2), 256, 0, stream>>>(h0, Wrt,         v, bb, h1, 1);
    k_layer<<<dim3(256, 2), 256, 0, stream>>>(h1, Wrt + 16384, v, bb, h0, 2);
    k_layer<<<dim3(256, 2), 256, 0, stream>>>(h0, Wrt + 32768, v, bb, h1, 3);

    k_convm<<<dim3(256), 256, 0, stream>>>(h1, Wcto, bct, x, out);
}